// Round 3
// baseline (345.508 us; speedup 1.0000x reference)
//
#include <hip/hip_runtime.h>

#define F_IN 128
#define NEG_SLOPE 0.2f
#define SCAN_CHUNK 2048  // 256 threads x 8 elements
#define CH 4096          // edges per block for bucket hist/scatter

typedef __attribute__((ext_vector_type(8))) short bf16x8;
typedef __attribute__((ext_vector_type(4))) float f32x4;

__device__ inline unsigned short f2bf(float f) {  // fp32 -> bf16 RNE
    unsigned int u = __float_as_uint(f);
    unsigned int r = (u + 0x7fffu + ((u >> 16) & 1u)) >> 16;
    return (unsigned short)r;
}
__device__ inline float bf2f(unsigned short h) { return __uint_as_float((unsigned int)h << 16); }
__device__ inline float bflo(unsigned int u) { return __uint_as_float(u << 16); }
__device__ inline float bfhi(unsigned int u) { return __uint_as_float(u & 0xffff0000u); }

// Swizzled ("fragment-order") B index for mfma_f32_16x16x32_bf16 consumption.
__device__ inline int bswiz(int n, int k) {
    int ct = n >> 4, rlo = n & 15, kk = k >> 5, q = (k >> 3) & 3, j = k & 7;
    return (((ct * 4 + kk) * 64 + q * 16 + rlo) << 3) + j;
}

// ---------------------------------------------------------------------------
// Prep: block 0 computes the 4 projected attention vectors v = W@att;
// blocks 1..96 build swizzled bf16 hi/lo copies of W1/W2.
// ---------------------------------------------------------------------------
__global__ void k_prep(const float* __restrict__ Ws1, const float* __restrict__ Wd1,
                       const float* __restrict__ as1, const float* __restrict__ ad1,
                       const float* __restrict__ Ws2, const float* __restrict__ Wd2,
                       const float* __restrict__ as2, const float* __restrict__ ad2,
                       float* __restrict__ vecs,
                       unsigned short* __restrict__ w1hi, unsigned short* __restrict__ w1lo,
                       unsigned short* __restrict__ w2hi, unsigned short* __restrict__ w2lo) {
    int bid = blockIdx.x, tid = threadIdx.x;
    if (bid == 0 && tid < 128) {
        int f = tid;
        float s1 = 0.f, d1 = 0.f, s2 = 0.f, d2 = 0.f;
        for (int c = 0; c < 128; ++c) {
            s1 += Ws1[f * 128 + c] * as1[c];
            d1 += Wd1[f * 128 + c] * ad1[c];
        }
        for (int c = 0; c < 64; ++c) {
            s2 += Ws2[f * 64 + c] * as2[c];
            d2 += Wd2[f * 64 + c] * ad2[c];
        }
        vecs[f] = s1; vecs[128 + f] = d1; vecs[256 + f] = s2; vecs[384 + f] = d2;
    } else if (bid >= 1 && bid < 65) {          // W1: n<128, k<128
        int idx = (bid - 1) * 256 + tid;        // < 16384
        int n = idx >> 7, k = idx & 127;
        float w = Ws1[k * 128 + n];
        unsigned short h = f2bf(w);
        int si = bswiz(n, k);
        w1hi[si] = h;
        w1lo[si] = f2bf(w - bf2f(h));
    } else if (bid >= 65 && bid < 97) {         // W2: n<64, k<128
        int idx = (bid - 65) * 256 + tid;       // < 8192
        int n = idx >> 7, k = idx & 127;
        float w = Ws2[k * 64 + n];
        unsigned short h = f2bf(w);
        int si = bswiz(n, k);
        w2hi[si] = h;
        w2lo[si] = f2bf(w - bf2f(h));
    }
}

// ---------------------------------------------------------------------------
// Atomic-free CSR build (round-2 win, kept).  Round-3 tweak: bscat payload
// packed to 4 B: (src<<8)|(dst&255) — src < 2^24 holds for N=100K.  Halves
// the random scatter write traffic and bfin's read traffic.
// ---------------------------------------------------------------------------

// Per-block histogram of buckets (dst>>8) -> bin-major table[bin][blk].
__global__ void k_bhist(const int* __restrict__ dsts, int* __restrict__ table,
                        int E, int NB, int nblk) {
    __shared__ int bins[512];
    int t = threadIdx.x, blk = blockIdx.x;
    for (int j = t; j < NB; j += 256) bins[j] = 0;
    __syncthreads();
    int base = blk * CH;
    #pragma unroll
    for (int k = 0; k < CH / 256; ++k) {
        int idx = base + k * 256 + t;
        if (idx < E) atomicAdd(&bins[dsts[idx] >> 8], 1);
    }
    __syncthreads();
    for (int j = t; j < NB; j += 256) table[(long long)j * nblk + blk] = bins[j];
}

__global__ void k_blocksum2(const int* __restrict__ in, int* __restrict__ bsum, int M) {
    __shared__ int sh[256];
    int t = threadIdx.x;
    long long base = (long long)blockIdx.x * SCAN_CHUNK + (long long)t * 8;
    int s = 0;
    #pragma unroll
    for (int k = 0; k < 8; ++k) {
        long long i = base + k;
        if (i < M) s += in[i];
    }
    sh[t] = s;
    __syncthreads();
    for (int off = 128; off; off >>= 1) {
        if (t < off) sh[t] += sh[t + off];
        __syncthreads();
    }
    if (t == 0) bsum[blockIdx.x] = sh[0];
}

// Exclusive scan of table IN PLACE (each thread reads its own 8 elements
// before writing them back; no cross-thread element access -> safe).
__global__ void k_scan2(int* __restrict__ io, const int* __restrict__ bsum, int M) {
    __shared__ int sh[256];
    int t = threadIdx.x, bid = blockIdx.x;
    int pre = 0;
    for (int b = 0; b < bid; ++b) pre += bsum[b];   // uniform -> s_loads
    long long base = (long long)bid * SCAN_CHUNK + (long long)t * 8;
    int loc[8];
    int s = 0;
    #pragma unroll
    for (int k = 0; k < 8; ++k) {
        long long i = base + k;
        int v = (i < M) ? io[i] : 0;
        loc[k] = s;
        s += v;
    }
    sh[t] = s;
    __syncthreads();
    for (int off = 1; off < 256; off <<= 1) {
        int tmp = (t >= off) ? sh[t - off] : 0;
        __syncthreads();
        sh[t] += tmp;
        __syncthreads();
    }
    int toff = pre + sh[t] - s;
    #pragma unroll
    for (int k = 0; k < 8; ++k) {
        long long i = base + k;
        if (i < M) io[i] = toff + loc[k];
    }
}

// Scatter edges into bucket-contiguous packed array: (src<<8)|(dst&255).
__global__ void k_bscat(const int* __restrict__ srcs, const int* __restrict__ dsts,
                        const int* __restrict__ table, int* __restrict__ pairA,
                        int E, int NB, int nblk) {
    __shared__ int offs[512];
    int t = threadIdx.x, blk = blockIdx.x;
    for (int j = t; j < NB; j += 256) offs[j] = table[(long long)j * nblk + blk];
    __syncthreads();
    int base = blk * CH;
    #pragma unroll
    for (int k = 0; k < CH / 256; ++k) {
        int idx = base + k * 256 + t;
        if (idx < E) {
            int d = dsts[idx], s = srcs[idx];
            int p = atomicAdd(&offs[d >> 8], 1);
            pairA[p] = (s << 8) | (d & 255);
        }
    }
}

// One block per bucket: LDS count over 256 local nodes -> LDS exclusive scan
// (writes rowptr directly) -> LDS running pointers place perm_src.
__global__ void k_bfin(const int* __restrict__ pairA, const int* __restrict__ table,
                       int* __restrict__ perm, int* __restrict__ rowptr,
                       int NB, int nblk, int N, int E) {
    __shared__ int scnt[256];
    __shared__ int sh[256];
    __shared__ int sptr[256];
    int t = threadIdx.x, b = blockIdx.x;
    int beg = table[(long long)b * nblk];
    int end = (b + 1 < NB) ? table[(long long)(b + 1) * nblk] : E;
    scnt[t] = 0;
    __syncthreads();
    for (int i = beg + t; i < end; i += 256) {
        atomicAdd(&scnt[pairA[i] & 255], 1);
    }
    __syncthreads();
    int c = scnt[t];
    sh[t] = c;
    __syncthreads();
    for (int off = 1; off < 256; off <<= 1) {
        int tmp = (t >= off) ? sh[t - off] : 0;
        __syncthreads();
        sh[t] += tmp;
        __syncthreads();
    }
    int excl = sh[t] - c;
    int node = (b << 8) + t;
    if (node < N) rowptr[node] = beg + excl;
    sptr[t] = beg + excl;
    __syncthreads();
    for (int i = beg + t; i < end; i += 256) {
        int u = pairA[i];
        int pos = atomicAdd(&sptr[u & 255], 1);
        perm[pos] = u >> 8;
    }
    if (b == NB - 1 && t == 0) rowptr[N] = E;
}

// ---------------------------------------------------------------------------
// Per-edge weight precompute (round 3): w[e] = exp(leaky(a_s[src]+a_d[dst])),
// computed ONCE per edge (quarter-wave per row; one lane per edge) instead of
// redundantly in all 64 lanes of the agg inner loop (~26us of duplicated VALU
// in agg128 alone).  a_s is 400KB -> gathers are L2-resident.  Same edge
// order and fp32 math as before -> aggregation stays bitwise identical.
// ---------------------------------------------------------------------------
__launch_bounds__(256)
__global__ void k_alpha(const int* __restrict__ rowptr, const int* __restrict__ perm,
                        const float* __restrict__ a_s, const float* __restrict__ a_d,
                        float* __restrict__ w, int N) {
    long long wid = ((long long)blockIdx.x * 256 + threadIdx.x) >> 6;
    int lane = threadIdx.x & 63;
    int g = lane >> 4, l = lane & 15;
    long long row = wid * 4 + g;   // 4 rows per wave, 16 lanes each
    if (row >= N) return;
    int beg = rowptr[row], end = rowptr[row + 1];
    float ad = a_d[row];
    for (int i = beg + l; i < end; i += 16) {
        float t = a_s[perm[i]] + ad;
        t = t > 0.f ? t : NEG_SLOPE * t;
        w[i] = __expf(t);
    }
}

// ---------------------------------------------------------------------------
// MFMA GEMM: H(bf16)[N][COLS] = X[N][128] @ W[128][COLS], fused rowdots.
// Swizzled B (coalesced 1 KB fragment loads) + 2 row-tiles per wave.
// Layer1 (!ABF16): fp32 X split bf16 hi/lo, 3 MFMAs/frag; Layer2: 2 MFMAs.
// ---------------------------------------------------------------------------
template <int COLS, bool ABF16>
__launch_bounds__(256)
__global__ void k_gemm_mfma(const void* __restrict__ Xv,
                            const unsigned short* __restrict__ Bh,
                            const unsigned short* __restrict__ Bl,
                            const float* __restrict__ vecs_s,
                            const float* __restrict__ vecs_d,
                            unsigned short* __restrict__ H,
                            float* __restrict__ a_s, float* __restrict__ a_d, int N) {
    int tid = threadIdx.x;
    int wave = tid >> 6, lane = tid & 63;
    int q = lane >> 4, rlo = lane & 15;
    long long wrow0 = (long long)blockIdx.x * 128 + wave * 32;

    bf16x8 Ahi[2][4], Alo[2][4];
    #pragma unroll
    for (int rt = 0; rt < 2; ++rt) {
        long long r = wrow0 + rt * 16 + rlo;
        long long rr = (r < N) ? r : (long long)(N - 1);  // clamp loads
        float ps = 0.f, pd = 0.f;
        #pragma unroll
        for (int kk = 0; kk < 4; ++kk) {
            int k0 = kk * 32 + q * 8;
            float xv[8];
            if constexpr (ABF16) {
                const unsigned short* Xu = (const unsigned short*)Xv;
                bf16x8 av = *(const bf16x8*)(Xu + rr * 128 + k0);
                Ahi[rt][kk] = av;
                #pragma unroll
                for (int j = 0; j < 8; ++j) xv[j] = bf2f((unsigned short)av[j]);
            } else {
                const float* Xf = (const float*)Xv;
                float4 x0 = *(const float4*)(Xf + rr * 128 + k0);
                float4 x1 = *(const float4*)(Xf + rr * 128 + k0 + 4);
                xv[0] = x0.x; xv[1] = x0.y; xv[2] = x0.z; xv[3] = x0.w;
                xv[4] = x1.x; xv[5] = x1.y; xv[6] = x1.z; xv[7] = x1.w;
                bf16x8 ah, al;
                #pragma unroll
                for (int j = 0; j < 8; ++j) {
                    unsigned short h = f2bf(xv[j]);
                    ah[j] = (short)h;
                    al[j] = (short)f2bf(xv[j] - bf2f(h));
                }
                Ahi[rt][kk] = ah; Alo[rt][kk] = al;
            }
            float4 vs0 = *(const float4*)(vecs_s + k0);
            float4 vs1 = *(const float4*)(vecs_s + k0 + 4);
            float4 vd0 = *(const float4*)(vecs_d + k0);
            float4 vd1 = *(const float4*)(vecs_d + k0 + 4);
            ps += xv[0] * vs0.x + xv[1] * vs0.y + xv[2] * vs0.z + xv[3] * vs0.w
                + xv[4] * vs1.x + xv[5] * vs1.y + xv[6] * vs1.z + xv[7] * vs1.w;
            pd += xv[0] * vd0.x + xv[1] * vd0.y + xv[2] * vd0.z + xv[3] * vd0.w
                + xv[4] * vd1.x + xv[5] * vd1.y + xv[6] * vd1.z + xv[7] * vd1.w;
        }
        ps += __shfl_xor(ps, 16); ps += __shfl_xor(ps, 32);
        pd += __shfl_xor(pd, 16); pd += __shfl_xor(pd, 32);
        if (q == 0 && r < N) { a_s[r] = ps; a_d[r] = pd; }
    }

    const bf16x8* Bh8 = (const bf16x8*)Bh;
    const bf16x8* Bl8 = (const bf16x8*)Bl;
    #pragma unroll 1   // keep rolled: bounds VGPRs; 8 loads in flight per iter
    for (int ct = 0; ct < COLS / 16; ++ct) {
        bf16x8 bh[4], bl[4];
        #pragma unroll
        for (int kk = 0; kk < 4; ++kk) {
            bh[kk] = Bh8[(ct * 4 + kk) * 64 + lane];
            bl[kk] = Bl8[(ct * 4 + kk) * 64 + lane];
        }
        f32x4 acc0 = {0.f, 0.f, 0.f, 0.f};
        f32x4 acc1 = {0.f, 0.f, 0.f, 0.f};
        #pragma unroll
        for (int kk = 0; kk < 4; ++kk) {
            acc0 = __builtin_amdgcn_mfma_f32_16x16x32_bf16(Ahi[0][kk], bh[kk], acc0, 0, 0, 0);
            acc1 = __builtin_amdgcn_mfma_f32_16x16x32_bf16(Ahi[1][kk], bh[kk], acc1, 0, 0, 0);
            if constexpr (!ABF16) {
                acc0 = __builtin_amdgcn_mfma_f32_16x16x32_bf16(Alo[0][kk], bh[kk], acc0, 0, 0, 0);
                acc1 = __builtin_amdgcn_mfma_f32_16x16x32_bf16(Alo[1][kk], bh[kk], acc1, 0, 0, 0);
            }
            acc0 = __builtin_amdgcn_mfma_f32_16x16x32_bf16(Ahi[0][kk], bl[kk], acc0, 0, 0, 0);
            acc1 = __builtin_amdgcn_mfma_f32_16x16x32_bf16(Ahi[1][kk], bl[kk], acc1, 0, 0, 0);
        }
        #pragma unroll
        for (int i2 = 0; i2 < 4; ++i2) {
            long long o0 = wrow0 + q * 4 + i2;
            long long o1 = wrow0 + 16 + q * 4 + i2;
            if (o0 < N) H[o0 * COLS + ct * 16 + rlo] = f2bf(acc0[i2]);
            if (o1 < N) H[o1 * COLS + ct * 16 + rlo] = f2bf(acc1[i2]);
        }
    }
}

// ---------------------------------------------------------------------------
// Layer-1 aggregate (C=128): one wave per dst row.  Inner loop is now pure
// gather + weighted accumulate (weights precomputed by k_alpha); 16-deep
// first tier for more misses in flight.  Edge order / fp add order preserved.
// ---------------------------------------------------------------------------
__launch_bounds__(256)
__global__ void k_agg128(const int* __restrict__ rowptr, const int* __restrict__ perm,
                         const float* __restrict__ wbuf,
                         const unsigned short* __restrict__ H, const float* __restrict__ bias,
                         unsigned short* __restrict__ out_bf, int N) {
    int wave = (int)(((long long)blockIdx.x * 256 + threadIdx.x) >> 6);
    int lane = threadIdx.x & 63;
    if (wave >= N) return;
    int beg = __builtin_amdgcn_readfirstlane(rowptr[wave]);
    int end = __builtin_amdgcn_readfirstlane(rowptr[wave + 1]);

    const unsigned int* H32 = (const unsigned int*)H;  // 64 uints/row
    float acc0 = 0.f, acc1 = 0.f, wsum = 0.f;
    int i = beg;
    for (; i + 16 <= end; i += 16) {
        int s[16];
        float wv[16];
        unsigned int v[16];
        #pragma unroll
        for (int j = 0; j < 16; ++j)
            s[j] = __builtin_amdgcn_readfirstlane(perm[i + j]);
        #pragma unroll
        for (int j = 0; j < 16; ++j)
            wv[j] = wbuf[i + j];
        #pragma unroll
        for (int j = 0; j < 16; ++j)
            v[j] = H32[(long long)s[j] * 64 + lane];
        #pragma unroll
        for (int j = 0; j < 16; ++j) {
            acc0 += wv[j] * bflo(v[j]);
            acc1 += wv[j] * bfhi(v[j]);
            wsum += wv[j];
        }
    }
    for (; i + 8 <= end; i += 8) {
        int s[8];
        float wv[8];
        unsigned int v[8];
        #pragma unroll
        for (int j = 0; j < 8; ++j)
            s[j] = __builtin_amdgcn_readfirstlane(perm[i + j]);
        #pragma unroll
        for (int j = 0; j < 8; ++j)
            wv[j] = wbuf[i + j];
        #pragma unroll
        for (int j = 0; j < 8; ++j)
            v[j] = H32[(long long)s[j] * 64 + lane];
        #pragma unroll
        for (int j = 0; j < 8; ++j) {
            acc0 += wv[j] * bflo(v[j]);
            acc1 += wv[j] * bfhi(v[j]);
            wsum += wv[j];
        }
    }
    for (; i < end; ++i) {
        int s = __builtin_amdgcn_readfirstlane(perm[i]);
        float w = wbuf[i];
        unsigned int v = H32[(long long)s * 64 + lane];
        acc0 += w * bflo(v); acc1 += w * bfhi(v);
        wsum += w;
    }
    float inv = (wsum > 0.f) ? __fdividef(1.f, wsum) : 0.f;  // deg-0 -> bias only
    float o0 = fmaxf(acc0 * inv + bias[2 * lane], 0.f);      // + b1, relu
    float o1 = fmaxf(acc1 * inv + bias[2 * lane + 1], 0.f);
    unsigned int pk = (unsigned int)f2bf(o0) | ((unsigned int)f2bf(o1) << 16);
    ((unsigned int*)out_bf)[(long long)wave * 64 + lane] = pk;
}

// ---------------------------------------------------------------------------
// Layer-2 aggregate (C=64): half-wave per edge; weights precomputed.
// ---------------------------------------------------------------------------
__launch_bounds__(256)
__global__ void k_agg64(const int* __restrict__ rowptr, const int* __restrict__ perm,
                        const float* __restrict__ wbuf,
                        const unsigned short* __restrict__ H, const float* __restrict__ bias,
                        float* __restrict__ out, int N) {
    int wave = (int)(((long long)blockIdx.x * 256 + threadIdx.x) >> 6);
    int lane = threadIdx.x & 63;
    if (wave >= N) return;
    int c = lane & 31, h = lane >> 5;  // half-wave id
    int beg = __builtin_amdgcn_readfirstlane(rowptr[wave]);
    int end = __builtin_amdgcn_readfirstlane(rowptr[wave + 1]);

    const unsigned int* H32 = (const unsigned int*)H;  // 32 uints/row
    float acc0 = 0.f, acc1 = 0.f, wsum = 0.f;
    int base = beg;
    for (; base + 16 <= end; base += 16) {
        int s[8];
        float wv[8];
        unsigned int v[8];
        #pragma unroll
        for (int j = 0; j < 8; ++j)
            s[j] = perm[base + h + 2 * j];
        #pragma unroll
        for (int j = 0; j < 8; ++j)
            wv[j] = wbuf[base + h + 2 * j];
        #pragma unroll
        for (int j = 0; j < 8; ++j)
            v[j] = H32[(long long)s[j] * 32 + c];
        #pragma unroll
        for (int j = 0; j < 8; ++j) {
            acc0 += wv[j] * bflo(v[j]);
            acc1 += wv[j] * bfhi(v[j]);
            wsum += wv[j];
        }
    }
    for (; base + 8 <= end; base += 8) {
        int s[4];
        float wv[4];
        unsigned int v[4];
        #pragma unroll
        for (int j = 0; j < 4; ++j)
            s[j] = perm[base + h + 2 * j];
        #pragma unroll
        for (int j = 0; j < 4; ++j)
            wv[j] = wbuf[base + h + 2 * j];
        #pragma unroll
        for (int j = 0; j < 4; ++j)
            v[j] = H32[(long long)s[j] * 32 + c];
        #pragma unroll
        for (int j = 0; j < 4; ++j) {
            acc0 += wv[j] * bflo(v[j]);
            acc1 += wv[j] * bfhi(v[j]);
            wsum += wv[j];
        }
    }
    for (int i = base + h; i < end; i += 2) {
        int s = perm[i];
        float w = wbuf[i];
        unsigned int v = H32[(long long)s * 32 + c];
        acc0 += w * bflo(v); acc1 += w * bfhi(v);
        wsum += w;
    }
    acc0 += __shfl_xor(acc0, 32);
    acc1 += __shfl_xor(acc1, 32);
    wsum += __shfl_xor(wsum, 32);
    if (h == 0) {
        float inv = (wsum > 0.f) ? __fdividef(1.f, wsum) : 0.f;
        float2 o;
        o.x = acc0 * inv + bias[2 * c];
        o.y = acc1 * inv + bias[2 * c + 1];
        *(float2*)(out + (long long)wave * 64 + 2 * c) = o;
    }
}

extern "C" void kernel_launch(void* const* d_in, const int* in_sizes, int n_in,
                              void* d_out, int out_size, void* d_ws, size_t ws_size,
                              hipStream_t stream) {
    const float* x   = (const float*)d_in[0];
    const int*   ei  = (const int*)d_in[1];
    const float* Ws1 = (const float*)d_in[2];
    const float* Wd1 = (const float*)d_in[3];
    const float* as1 = (const float*)d_in[4];
    const float* ad1 = (const float*)d_in[5];
    const float* b1  = (const float*)d_in[6];
    const float* Ws2 = (const float*)d_in[7];
    const float* Wd2 = (const float*)d_in[8];
    const float* as2 = (const float*)d_in[9];
    const float* ad2 = (const float*)d_in[10];
    const float* b2  = (const float*)d_in[11];
    float* out = (float*)d_out;

    const int N = in_sizes[0] / F_IN;   // 100000
    const int E = in_sizes[1] / 2;      // 1600000
    const int* srcs = ei;
    const int* dsts = ei + E;

    const int nblk = (E + CH - 1) / CH;      // 391 edge chunks
    const int NB   = (N + 255) >> 8;         // 391 buckets (<=512 required)
    const int M    = NB * nblk;              // table entries (~153K)
    const int nb2  = (M + SCAN_CHUNK - 1) / SCAN_CHUNK;

    // Workspace (~66.1 MB, same as round-1-proven).  All CSR scratch
    // (pairA, table) aliases inside x2bf (dead until k_agg128 writes it).
    unsigned short* hbuf = (unsigned short*)d_ws;              // N*128 bf16
    unsigned short* x2bf = hbuf + (size_t)N * 128;             // N*128 bf16
    int*   perm   = (int*)(x2bf + (size_t)N * 128);            // E
    float* a_s1   = (float*)(perm + E);
    float* a_d1   = a_s1 + N;
    float* a_s2   = a_d1 + N;
    float* a_d2   = a_s2 + N;
    float* wbuf   = a_d2 + N;                                  // E floats (per-edge weights)
    int*   rowptr = (int*)(wbuf + E);                          // N+1 (pad to +4)
    int*   bsum   = rowptr + N + 4;                            // 128
    unsigned short* w1hi = (unsigned short*)(bsum + 128);      // 16384 (swizzled)
    unsigned short* w1lo = w1hi + 16384;
    unsigned short* w2hi = w1lo + 16384;                       // 8192 (swizzled)
    unsigned short* w2lo = w2hi + 8192;
    float* vecs   = (float*)(w2lo + 8192);                     // 512
    int*   pairA  = (int*)x2bf;                                // E ints (alias)
    int*   table  = pairA + E;                                 // M ints (alias, scanned in place)

    // ---- prep (attention vecs + swizzled W hi/lo) ----
    k_prep<<<97, 256, 0, stream>>>(Ws1, Wd1, as1, ad1, Ws2, Wd2, as2, ad2,
                                   vecs, w1hi, w1lo, w2hi, w2lo);
    // ---- CSR build: bucket hist -> in-place scan -> scatter -> LDS finalize ----
    k_bhist<<<nblk, 256, 0, stream>>>(dsts, table, E, NB, nblk);
    k_blocksum2<<<nb2, 256, 0, stream>>>(table, bsum, M);
    k_scan2<<<nb2, 256, 0, stream>>>(table, bsum, M);
    k_bscat<<<nblk, 256, 0, stream>>>(srcs, dsts, table, pairA, E, NB, nblk);
    k_bfin<<<NB, 256, 0, stream>>>(pairA, table, perm, rowptr, NB, nblk, N, E);

    const int ablocks = (((N + 3) / 4) * 64 + 255) / 256;  // 4 rows/wave

    // ---- Layer 1: fp32 X, split-bf16 MFMA ----
    k_gemm_mfma<128, false><<<(N + 127) / 128, 256, 0, stream>>>(
        x, w1hi, w1lo, vecs, vecs + 128, hbuf, a_s1, a_d1, N);
    k_alpha<<<ablocks, 256, 0, stream>>>(rowptr, perm, a_s1, a_d1, wbuf, N);
    k_agg128<<<(N + 3) / 4, 256, 0, stream>>>(
        rowptr, perm, wbuf, hbuf, b1, x2bf, N);

    // ---- Layer 2: bf16 X (relu'd, b1 folded in by agg) ----
    k_gemm_mfma<64, true><<<(N + 127) / 128, 256, 0, stream>>>(
        x2bf, w2hi, w2lo, vecs + 256, vecs + 384, hbuf, a_s2, a_d2, N);
    k_alpha<<<ablocks, 256, 0, stream>>>(rowptr, perm, a_s2, a_d2, wbuf, N);
    k_agg64<<<(N + 3) / 4, 256, 0, stream>>>(
        rowptr, perm, wbuf, hbuf, b2, out, N);
}

// Round 4
// 319.348 us; speedup vs baseline: 1.0819x; 1.0819x over previous
//
#include <hip/hip_runtime.h>

#define F_IN 128
#define NEG_SLOPE 0.2f
#define SCAN_CHUNK 2048  // 256 threads x 8 elements
#define CH 4096          // edges per block for bucket hist/scatter

typedef __attribute__((ext_vector_type(8))) short bf16x8;
typedef __attribute__((ext_vector_type(4))) float f32x4;

__device__ inline unsigned short f2bf(float f) {  // fp32 -> bf16 RNE
    unsigned int u = __float_as_uint(f);
    unsigned int r = (u + 0x7fffu + ((u >> 16) & 1u)) >> 16;
    return (unsigned short)r;
}
__device__ inline float bf2f(unsigned short h) { return __uint_as_float((unsigned int)h << 16); }
__device__ inline float bflo(unsigned int u) { return __uint_as_float(u << 16); }
__device__ inline float bfhi(unsigned int u) { return __uint_as_float(u & 0xffff0000u); }

// Swizzled ("fragment-order") B index for mfma_f32_16x16x32_bf16 consumption.
__device__ inline int bswiz(int n, int k) {
    int ct = n >> 4, rlo = n & 15, kk = k >> 5, q = (k >> 3) & 3, j = k & 7;
    return (((ct * 4 + kk) * 64 + q * 16 + rlo) << 3) + j;
}

// ---------------------------------------------------------------------------
// Prep: block 0 computes the 4 projected attention vectors v = W@att;
// blocks 1..96 build swizzled bf16 hi/lo copies of W1/W2.
// ---------------------------------------------------------------------------
__global__ void k_prep(const float* __restrict__ Ws1, const float* __restrict__ Wd1,
                       const float* __restrict__ as1, const float* __restrict__ ad1,
                       const float* __restrict__ Ws2, const float* __restrict__ Wd2,
                       const float* __restrict__ as2, const float* __restrict__ ad2,
                       float* __restrict__ vecs,
                       unsigned short* __restrict__ w1hi, unsigned short* __restrict__ w1lo,
                       unsigned short* __restrict__ w2hi, unsigned short* __restrict__ w2lo) {
    int bid = blockIdx.x, tid = threadIdx.x;
    if (bid == 0 && tid < 128) {
        int f = tid;
        float s1 = 0.f, d1 = 0.f, s2 = 0.f, d2 = 0.f;
        for (int c = 0; c < 128; ++c) {
            s1 += Ws1[f * 128 + c] * as1[c];
            d1 += Wd1[f * 128 + c] * ad1[c];
        }
        for (int c = 0; c < 64; ++c) {
            s2 += Ws2[f * 64 + c] * as2[c];
            d2 += Wd2[f * 64 + c] * ad2[c];
        }
        vecs[f] = s1; vecs[128 + f] = d1; vecs[256 + f] = s2; vecs[384 + f] = d2;
    } else if (bid >= 1 && bid < 65) {          // W1: n<128, k<128
        int idx = (bid - 1) * 256 + tid;        // < 16384
        int n = idx >> 7, k = idx & 127;
        float w = Ws1[k * 128 + n];
        unsigned short h = f2bf(w);
        int si = bswiz(n, k);
        w1hi[si] = h;
        w1lo[si] = f2bf(w - bf2f(h));
    } else if (bid >= 65 && bid < 97) {         // W2: n<64, k<128
        int idx = (bid - 65) * 256 + tid;       // < 8192
        int n = idx >> 7, k = idx & 127;
        float w = Ws2[k * 64 + n];
        unsigned short h = f2bf(w);
        int si = bswiz(n, k);
        w2hi[si] = h;
        w2lo[si] = f2bf(w - bf2f(h));
    }
}

// ---------------------------------------------------------------------------
// Atomic-free CSR build (round-2 win).  bscat payload packed to 4 B:
// (src<<8)|(dst&255) — src < 2^24 holds for N=100K.
// ---------------------------------------------------------------------------

// Per-block histogram of buckets (dst>>8) -> bin-major table[bin][blk].
__global__ void k_bhist(const int* __restrict__ dsts, int* __restrict__ table,
                        int E, int NB, int nblk) {
    __shared__ int bins[512];
    int t = threadIdx.x, blk = blockIdx.x;
    for (int j = t; j < NB; j += 256) bins[j] = 0;
    __syncthreads();
    int base = blk * CH;
    #pragma unroll
    for (int k = 0; k < CH / 256; ++k) {
        int idx = base + k * 256 + t;
        if (idx < E) atomicAdd(&bins[dsts[idx] >> 8], 1);
    }
    __syncthreads();
    for (int j = t; j < NB; j += 256) table[(long long)j * nblk + blk] = bins[j];
}

__global__ void k_blocksum2(const int* __restrict__ in, int* __restrict__ bsum, int M) {
    __shared__ int sh[256];
    int t = threadIdx.x;
    long long base = (long long)blockIdx.x * SCAN_CHUNK + (long long)t * 8;
    int s = 0;
    #pragma unroll
    for (int k = 0; k < 8; ++k) {
        long long i = base + k;
        if (i < M) s += in[i];
    }
    sh[t] = s;
    __syncthreads();
    for (int off = 128; off; off >>= 1) {
        if (t < off) sh[t] += sh[t + off];
        __syncthreads();
    }
    if (t == 0) bsum[blockIdx.x] = sh[0];
}

// Exclusive scan of table IN PLACE (each thread reads its own 8 elements
// before writing them back; no cross-thread element access -> safe).
__global__ void k_scan2(int* __restrict__ io, const int* __restrict__ bsum, int M) {
    __shared__ int sh[256];
    int t = threadIdx.x, bid = blockIdx.x;
    int pre = 0;
    for (int b = 0; b < bid; ++b) pre += bsum[b];   // uniform -> s_loads
    long long base = (long long)bid * SCAN_CHUNK + (long long)t * 8;
    int loc[8];
    int s = 0;
    #pragma unroll
    for (int k = 0; k < 8; ++k) {
        long long i = base + k;
        int v = (i < M) ? io[i] : 0;
        loc[k] = s;
        s += v;
    }
    sh[t] = s;
    __syncthreads();
    for (int off = 1; off < 256; off <<= 1) {
        int tmp = (t >= off) ? sh[t - off] : 0;
        __syncthreads();
        sh[t] += tmp;
        __syncthreads();
    }
    int toff = pre + sh[t] - s;
    #pragma unroll
    for (int k = 0; k < 8; ++k) {
        long long i = base + k;
        if (i < M) io[i] = toff + loc[k];
    }
}

// Scatter edges into bucket-contiguous packed array: (src<<8)|(dst&255).
__global__ void k_bscat(const int* __restrict__ srcs, const int* __restrict__ dsts,
                        const int* __restrict__ table, int* __restrict__ pairA,
                        int E, int NB, int nblk) {
    __shared__ int offs[512];
    int t = threadIdx.x, blk = blockIdx.x;
    for (int j = t; j < NB; j += 256) offs[j] = table[(long long)j * nblk + blk];
    __syncthreads();
    int base = blk * CH;
    #pragma unroll
    for (int k = 0; k < CH / 256; ++k) {
        int idx = base + k * 256 + t;
        if (idx < E) {
            int d = dsts[idx], s = srcs[idx];
            int p = atomicAdd(&offs[d >> 8], 1);
            pairA[p] = (s << 8) | (d & 255);
        }
    }
}

// One block per bucket: LDS count over 256 local nodes -> LDS exclusive scan
// (writes rowptr directly) -> LDS running pointers place perm_src.
__global__ void k_bfin(const int* __restrict__ pairA, const int* __restrict__ table,
                       int* __restrict__ perm, int* __restrict__ rowptr,
                       int NB, int nblk, int N, int E) {
    __shared__ int scnt[256];
    __shared__ int sh[256];
    __shared__ int sptr[256];
    int t = threadIdx.x, b = blockIdx.x;
    int beg = table[(long long)b * nblk];
    int end = (b + 1 < NB) ? table[(long long)(b + 1) * nblk] : E;
    scnt[t] = 0;
    __syncthreads();
    for (int i = beg + t; i < end; i += 256) {
        atomicAdd(&scnt[pairA[i] & 255], 1);
    }
    __syncthreads();
    int c = scnt[t];
    sh[t] = c;
    __syncthreads();
    for (int off = 1; off < 256; off <<= 1) {
        int tmp = (t >= off) ? sh[t - off] : 0;
        __syncthreads();
        sh[t] += tmp;
        __syncthreads();
    }
    int excl = sh[t] - c;
    int node = (b << 8) + t;
    if (node < N) rowptr[node] = beg + excl;
    sptr[t] = beg + excl;
    __syncthreads();
    for (int i = beg + t; i < end; i += 256) {
        int u = pairA[i];
        int pos = atomicAdd(&sptr[u & 255], 1);
        perm[pos] = u >> 8;
    }
    if (b == NB - 1 && t == 0) rowptr[N] = E;
}

// ---------------------------------------------------------------------------
// MFMA GEMM: H(bf16)[N][COLS] = X[N][128] @ W[128][COLS], fused rowdots.
// Swizzled B (coalesced 1 KB fragment loads) + 2 row-tiles per wave.
// Layer1 (!ABF16): fp32 X split bf16 hi/lo, 3 MFMAs/frag; Layer2: 2 MFMAs.
// ---------------------------------------------------------------------------
template <int COLS, bool ABF16>
__launch_bounds__(256)
__global__ void k_gemm_mfma(const void* __restrict__ Xv,
                            const unsigned short* __restrict__ Bh,
                            const unsigned short* __restrict__ Bl,
                            const float* __restrict__ vecs_s,
                            const float* __restrict__ vecs_d,
                            unsigned short* __restrict__ H,
                            float* __restrict__ a_s, float* __restrict__ a_d, int N) {
    int tid = threadIdx.x;
    int wave = tid >> 6, lane = tid & 63;
    int q = lane >> 4, rlo = lane & 15;
    long long wrow0 = (long long)blockIdx.x * 128 + wave * 32;

    bf16x8 Ahi[2][4], Alo[2][4];
    #pragma unroll
    for (int rt = 0; rt < 2; ++rt) {
        long long r = wrow0 + rt * 16 + rlo;
        long long rr = (r < N) ? r : (long long)(N - 1);  // clamp loads
        float ps = 0.f, pd = 0.f;
        #pragma unroll
        for (int kk = 0; kk < 4; ++kk) {
            int k0 = kk * 32 + q * 8;
            float xv[8];
            if constexpr (ABF16) {
                const unsigned short* Xu = (const unsigned short*)Xv;
                bf16x8 av = *(const bf16x8*)(Xu + rr * 128 + k0);
                Ahi[rt][kk] = av;
                #pragma unroll
                for (int j = 0; j < 8; ++j) xv[j] = bf2f((unsigned short)av[j]);
            } else {
                const float* Xf = (const float*)Xv;
                float4 x0 = *(const float4*)(Xf + rr * 128 + k0);
                float4 x1 = *(const float4*)(Xf + rr * 128 + k0 + 4);
                xv[0] = x0.x; xv[1] = x0.y; xv[2] = x0.z; xv[3] = x0.w;
                xv[4] = x1.x; xv[5] = x1.y; xv[6] = x1.z; xv[7] = x1.w;
                bf16x8 ah, al;
                #pragma unroll
                for (int j = 0; j < 8; ++j) {
                    unsigned short h = f2bf(xv[j]);
                    ah[j] = (short)h;
                    al[j] = (short)f2bf(xv[j] - bf2f(h));
                }
                Ahi[rt][kk] = ah; Alo[rt][kk] = al;
            }
            float4 vs0 = *(const float4*)(vecs_s + k0);
            float4 vs1 = *(const float4*)(vecs_s + k0 + 4);
            float4 vd0 = *(const float4*)(vecs_d + k0);
            float4 vd1 = *(const float4*)(vecs_d + k0 + 4);
            ps += xv[0] * vs0.x + xv[1] * vs0.y + xv[2] * vs0.z + xv[3] * vs0.w
                + xv[4] * vs1.x + xv[5] * vs1.y + xv[6] * vs1.z + xv[7] * vs1.w;
            pd += xv[0] * vd0.x + xv[1] * vd0.y + xv[2] * vd0.z + xv[3] * vd0.w
                + xv[4] * vd1.x + xv[5] * vd1.y + xv[6] * vd1.z + xv[7] * vd1.w;
        }
        ps += __shfl_xor(ps, 16); ps += __shfl_xor(ps, 32);
        pd += __shfl_xor(pd, 16); pd += __shfl_xor(pd, 32);
        if (q == 0 && r < N) { a_s[r] = ps; a_d[r] = pd; }
    }

    const bf16x8* Bh8 = (const bf16x8*)Bh;
    const bf16x8* Bl8 = (const bf16x8*)Bl;
    #pragma unroll 1   // keep rolled: bounds VGPRs; 8 loads in flight per iter
    for (int ct = 0; ct < COLS / 16; ++ct) {
        bf16x8 bh[4], bl[4];
        #pragma unroll
        for (int kk = 0; kk < 4; ++kk) {
            bh[kk] = Bh8[(ct * 4 + kk) * 64 + lane];
            bl[kk] = Bl8[(ct * 4 + kk) * 64 + lane];
        }
        f32x4 acc0 = {0.f, 0.f, 0.f, 0.f};
        f32x4 acc1 = {0.f, 0.f, 0.f, 0.f};
        #pragma unroll
        for (int kk = 0; kk < 4; ++kk) {
            acc0 = __builtin_amdgcn_mfma_f32_16x16x32_bf16(Ahi[0][kk], bh[kk], acc0, 0, 0, 0);
            acc1 = __builtin_amdgcn_mfma_f32_16x16x32_bf16(Ahi[1][kk], bh[kk], acc1, 0, 0, 0);
            if constexpr (!ABF16) {
                acc0 = __builtin_amdgcn_mfma_f32_16x16x32_bf16(Alo[0][kk], bh[kk], acc0, 0, 0, 0);
                acc1 = __builtin_amdgcn_mfma_f32_16x16x32_bf16(Alo[1][kk], bh[kk], acc1, 0, 0, 0);
            }
            acc0 = __builtin_amdgcn_mfma_f32_16x16x32_bf16(Ahi[0][kk], bl[kk], acc0, 0, 0, 0);
            acc1 = __builtin_amdgcn_mfma_f32_16x16x32_bf16(Ahi[1][kk], bl[kk], acc1, 0, 0, 0);
        }
        #pragma unroll
        for (int i2 = 0; i2 < 4; ++i2) {
            long long o0 = wrow0 + q * 4 + i2;
            long long o1 = wrow0 + 16 + q * 4 + i2;
            if (o0 < N) H[o0 * COLS + ct * 16 + rlo] = f2bf(acc0[i2]);
            if (o1 < N) H[o1 * COLS + ct * 16 + rlo] = f2bf(acc1[i2]);
        }
    }
}

// ---------------------------------------------------------------------------
// Layer-1 aggregate (C=128): one wave per dst row.  Round 4: weights computed
// lane-parallel (lanes 0-15 each compute ONE exp for the 16-edge batch) and
// broadcast via v_readlane (j is an unroll constant -> SGPR), which also
// replaces the 16 scalar perm loads.  Round-3's separate k_alpha kernel
// (latency-bound, ~20us/layer + 12.8MB wbuf traffic) is deleted.
// ---------------------------------------------------------------------------
__launch_bounds__(256)
__global__ void k_agg128(const int* __restrict__ rowptr, const int* __restrict__ perm,
                         const float* __restrict__ a_s, const float* __restrict__ a_d,
                         const unsigned short* __restrict__ H, const float* __restrict__ bias,
                         unsigned short* __restrict__ out_bf, int N) {
    int wave = (int)(((long long)blockIdx.x * 256 + threadIdx.x) >> 6);
    int lane = threadIdx.x & 63;
    if (wave >= N) return;
    int beg = __builtin_amdgcn_readfirstlane(rowptr[wave]);
    int end = __builtin_amdgcn_readfirstlane(rowptr[wave + 1]);
    float ad = __uint_as_float(__builtin_amdgcn_readfirstlane(__float_as_uint(a_d[wave])));

    const unsigned int* H32 = (const unsigned int*)H;  // 64 uints/row
    float acc0 = 0.f, acc1 = 0.f, wsum = 0.f;
    int i = beg;
    for (; i + 16 <= end; i += 16) {
        int pl = perm[i + (lane & 15)];      // lanes 0-15 carry the batch
        float t = a_s[pl] + ad;              // one gather+exp per lane, not 16
        t = t > 0.f ? t : NEG_SLOPE * t;
        float wl = __expf(t);
        unsigned int v[16];
        #pragma unroll
        for (int j = 0; j < 16; ++j) {
            int sj = __builtin_amdgcn_readlane(pl, j);        // SGPR row index
            v[j] = H32[(long long)sj * 64 + lane];
        }
        #pragma unroll
        for (int j = 0; j < 16; ++j) {
            float wj = __uint_as_float(
                (unsigned int)__builtin_amdgcn_readlane((int)__float_as_uint(wl), j));
            acc0 += wj * bflo(v[j]);
            acc1 += wj * bfhi(v[j]);
            wsum += wj;
        }
    }
    for (; i + 8 <= end; i += 8) {
        int pl = perm[i + (lane & 7)];
        float t = a_s[pl] + ad;
        t = t > 0.f ? t : NEG_SLOPE * t;
        float wl = __expf(t);
        unsigned int v[8];
        #pragma unroll
        for (int j = 0; j < 8; ++j) {
            int sj = __builtin_amdgcn_readlane(pl, j);
            v[j] = H32[(long long)sj * 64 + lane];
        }
        #pragma unroll
        for (int j = 0; j < 8; ++j) {
            float wj = __uint_as_float(
                (unsigned int)__builtin_amdgcn_readlane((int)__float_as_uint(wl), j));
            acc0 += wj * bflo(v[j]);
            acc1 += wj * bfhi(v[j]);
            wsum += wj;
        }
    }
    for (; i < end; ++i) {                   // tail <8 edges: redundant compute ok
        int s = __builtin_amdgcn_readfirstlane(perm[i]);
        unsigned int v = H32[(long long)s * 64 + lane];
        float t = a_s[s] + ad;
        t = t > 0.f ? t : NEG_SLOPE * t;
        float w = __expf(t);
        acc0 += w * bflo(v); acc1 += w * bfhi(v);
        wsum += w;
    }
    float inv = (wsum > 0.f) ? __fdividef(1.f, wsum) : 0.f;  // deg-0 -> bias only
    float o0 = fmaxf(acc0 * inv + bias[2 * lane], 0.f);      // + b1, relu
    float o1 = fmaxf(acc1 * inv + bias[2 * lane + 1], 0.f);
    unsigned int pk = (unsigned int)f2bf(o0) | ((unsigned int)f2bf(o1) << 16);
    ((unsigned int*)out_bf)[(long long)wave * 64 + lane] = pk;
}

// ---------------------------------------------------------------------------
// Layer-2 aggregate (C=64): half-wave per edge.  Weights lane-parallel
// (lanes 0-15 compute the 16-edge batch) and distributed via __shfl
// (per-lane index h+2j -> bpermute, DS pipe).
// ---------------------------------------------------------------------------
__launch_bounds__(256)
__global__ void k_agg64(const int* __restrict__ rowptr, const int* __restrict__ perm,
                        const float* __restrict__ a_s, const float* __restrict__ a_d,
                        const unsigned short* __restrict__ H, const float* __restrict__ bias,
                        float* __restrict__ out, int N) {
    int wave = (int)(((long long)blockIdx.x * 256 + threadIdx.x) >> 6);
    int lane = threadIdx.x & 63;
    if (wave >= N) return;
    int c = lane & 31, h = lane >> 5;  // half-wave id
    int beg = __builtin_amdgcn_readfirstlane(rowptr[wave]);
    int end = __builtin_amdgcn_readfirstlane(rowptr[wave + 1]);
    float ad = __uint_as_float(__builtin_amdgcn_readfirstlane(__float_as_uint(a_d[wave])));

    const unsigned int* H32 = (const unsigned int*)H;  // 32 uints/row
    float acc0 = 0.f, acc1 = 0.f, wsum = 0.f;
    int base = beg;
    for (; base + 16 <= end; base += 16) {
        int pl = perm[base + (lane & 15)];
        float t = a_s[pl] + ad;
        t = t > 0.f ? t : NEG_SLOPE * t;
        float wl = __expf(t);
        int sv[8];
        float wv[8];
        unsigned int v[8];
        #pragma unroll
        for (int j = 0; j < 8; ++j) {
            sv[j] = __shfl(pl, h + 2 * j);
            wv[j] = __shfl(wl, h + 2 * j);
        }
        #pragma unroll
        for (int j = 0; j < 8; ++j)
            v[j] = H32[(long long)sv[j] * 32 + c];
        #pragma unroll
        for (int j = 0; j < 8; ++j) {
            acc0 += wv[j] * bflo(v[j]);
            acc1 += wv[j] * bfhi(v[j]);
            wsum += wv[j];
        }
    }
    for (; base + 8 <= end; base += 8) {
        int pl = perm[base + (lane & 7)];
        float t = a_s[pl] + ad;
        t = t > 0.f ? t : NEG_SLOPE * t;
        float wl = __expf(t);
        int sv[4];
        float wv[4];
        unsigned int v[4];
        #pragma unroll
        for (int j = 0; j < 4; ++j) {
            sv[j] = __shfl(pl, h + 2 * j);
            wv[j] = __shfl(wl, h + 2 * j);
        }
        #pragma unroll
        for (int j = 0; j < 4; ++j)
            v[j] = H32[(long long)sv[j] * 32 + c];
        #pragma unroll
        for (int j = 0; j < 4; ++j) {
            acc0 += wv[j] * bflo(v[j]);
            acc1 += wv[j] * bfhi(v[j]);
            wsum += wv[j];
        }
    }
    for (int i = base + h; i < end; i += 2) {   // tail: redundant within half
        int s = perm[i];
        unsigned int v = H32[(long long)s * 32 + c];
        float t = a_s[s] + ad;
        t = t > 0.f ? t : NEG_SLOPE * t;
        float w = __expf(t);
        acc0 += w * bflo(v); acc1 += w * bfhi(v);
        wsum += w;
    }
    acc0 += __shfl_xor(acc0, 32);
    acc1 += __shfl_xor(acc1, 32);
    wsum += __shfl_xor(wsum, 32);
    if (h == 0) {
        float inv = (wsum > 0.f) ? __fdividef(1.f, wsum) : 0.f;
        float2 o;
        o.x = acc0 * inv + bias[2 * c];
        o.y = acc1 * inv + bias[2 * c + 1];
        *(float2*)(out + (long long)wave * 64 + 2 * c) = o;
    }
}

extern "C" void kernel_launch(void* const* d_in, const int* in_sizes, int n_in,
                              void* d_out, int out_size, void* d_ws, size_t ws_size,
                              hipStream_t stream) {
    const float* x   = (const float*)d_in[0];
    const int*   ei  = (const int*)d_in[1];
    const float* Ws1 = (const float*)d_in[2];
    const float* Wd1 = (const float*)d_in[3];
    const float* as1 = (const float*)d_in[4];
    const float* ad1 = (const float*)d_in[5];
    const float* b1  = (const float*)d_in[6];
    const float* Ws2 = (const float*)d_in[7];
    const float* Wd2 = (const float*)d_in[8];
    const float* as2 = (const float*)d_in[9];
    const float* ad2 = (const float*)d_in[10];
    const float* b2  = (const float*)d_in[11];
    float* out = (float*)d_out;

    const int N = in_sizes[0] / F_IN;   // 100000
    const int E = in_sizes[1] / 2;      // 1600000
    const int* srcs = ei;
    const int* dsts = ei + E;

    const int nblk = (E + CH - 1) / CH;      // 391 edge chunks
    const int NB   = (N + 255) >> 8;         // 391 buckets (<=512 required)
    const int M    = NB * nblk;              // table entries (~153K)
    const int nb2  = (M + SCAN_CHUNK - 1) / SCAN_CHUNK;

    // Workspace (~60 MB).  CSR scratch (pairA, table) aliases inside x2bf
    // (dead until k_agg128 writes it).
    unsigned short* hbuf = (unsigned short*)d_ws;              // N*128 bf16
    unsigned short* x2bf = hbuf + (size_t)N * 128;             // N*128 bf16
    int*   perm   = (int*)(x2bf + (size_t)N * 128);            // E
    float* a_s1   = (float*)(perm + E);
    float* a_d1   = a_s1 + N;
    float* a_s2   = a_d1 + N;
    float* a_d2   = a_s2 + N;
    int*   rowptr = (int*)(a_d2 + N);                          // N+1 (pad to +4)
    int*   bsum   = rowptr + N + 4;                            // 128
    unsigned short* w1hi = (unsigned short*)(bsum + 128);      // 16384 (swizzled)
    unsigned short* w1lo = w1hi + 16384;
    unsigned short* w2hi = w1lo + 16384;                       // 8192 (swizzled)
    unsigned short* w2lo = w2hi + 8192;
    float* vecs   = (float*)(w2lo + 8192);                     // 512
    int*   pairA  = (int*)x2bf;                                // E ints (alias)
    int*   table  = pairA + E;                                 // M ints (alias, scanned in place)

    // ---- prep (attention vecs + swizzled W hi/lo) ----
    k_prep<<<97, 256, 0, stream>>>(Ws1, Wd1, as1, ad1, Ws2, Wd2, as2, ad2,
                                   vecs, w1hi, w1lo, w2hi, w2lo);
    // ---- CSR build: bucket hist -> in-place scan -> scatter -> LDS finalize ----
    k_bhist<<<nblk, 256, 0, stream>>>(dsts, table, E, NB, nblk);
    k_blocksum2<<<nb2, 256, 0, stream>>>(table, bsum, M);
    k_scan2<<<nb2, 256, 0, stream>>>(table, bsum, M);
    k_bscat<<<nblk, 256, 0, stream>>>(srcs, dsts, table, pairA, E, NB, nblk);
    k_bfin<<<NB, 256, 0, stream>>>(pairA, table, perm, rowptr, NB, nblk, N, E);

    // ---- Layer 1: fp32 X, split-bf16 MFMA ----
    k_gemm_mfma<128, false><<<(N + 127) / 128, 256, 0, stream>>>(
        x, w1hi, w1lo, vecs, vecs + 128, hbuf, a_s1, a_d1, N);
    k_agg128<<<(N + 3) / 4, 256, 0, stream>>>(
        rowptr, perm, a_s1, a_d1, hbuf, b1, x2bf, N);

    // ---- Layer 2: bf16 X (relu'd, b1 folded in by agg) ----
    k_gemm_mfma<64, true><<<(N + 127) / 128, 256, 0, stream>>>(
        x2bf, w2hi, w2lo, vecs + 256, vecs + 384, hbuf, a_s2, a_d2, N);
    k_agg64<<<(N + 3) / 4, 256, 0, stream>>>(
        rowptr, perm, a_s2, a_d2, hbuf, b2, out, N);
}